// Round 3
// baseline (277.534 us; speedup 1.0000x reference)
//
#include <hip/hip_runtime.h>
#include <stdint.h>

typedef unsigned short u16;
typedef __bf16 bf16x8 __attribute__((ext_vector_type(8)));
typedef float f32x4 __attribute__((ext_vector_type(4)));

#define MM 2
#define NN 8
#define CC 1024
#define DD 256
#define BB 32
#define SS 512

__device__ __forceinline__ u16 f2bf(float f) {
  uint32_t u = __float_as_uint(f);
  u += 0x7FFFu + ((u >> 16) & 1u);   // round-to-nearest-even
  return (u16)(u >> 16);
}

__device__ __forceinline__ void async16(const void* g, void* l) {
  __builtin_amdgcn_global_load_lds(
      (const __attribute__((address_space(1))) uint32_t*)g,
      (__attribute__((address_space(3))) uint32_t*)l, 16, 0, 0);
}

// ---------------- prep: cvt x + transpose both weights, one launch ----------
#define CVT_BLOCKS 16384
#define T_BLOCKS 4096
__global__ __launch_bounds__(256) void prep(
    const float* __restrict__ x, u16* __restrict__ xb,
    const float* __restrict__ dw, u16* __restrict__ wdT,
    const float* __restrict__ uw, u16* __restrict__ wuT) {
  const int bid = blockIdx.x;
  if (bid < CVT_BLOCKS) {
    int i = (bid * 256 + threadIdx.x) * 4;
    float4 v = *reinterpret_cast<const float4*>(x + i);
    u16 o[4] = {f2bf(v.x), f2bf(v.y), f2bf(v.z), f2bf(v.w)};
    *reinterpret_cast<uint2*>(xb + i) = *reinterpret_cast<const uint2*>(o);
    return;
  }
  __shared__ float tile[32][33];
  const float* src;
  u16* dst;
  int R, L, bx, by, slab;
  if (bid < CVT_BLOCKS + T_BLOCKS) {
    int t = bid - CVT_BLOCKS;
    slab = t >> 8;
    int t2 = t & 255;
    bx = t2 & 7;  by = t2 >> 3;    // L/32=8, R/32=32
    R = CC; L = DD;
    src = dw; dst = wdT;
  } else {
    int t = bid - CVT_BLOCKS - T_BLOCKS;
    slab = t >> 8;
    int t2 = t & 255;
    bx = t2 & 31; by = t2 >> 5;    // L/32=32, R/32=8
    R = DD; L = CC;
    src = uw; dst = wuT;
  }
  src += (size_t)slab * R * L;
  dst += (size_t)slab * R * L;
  const int c0 = bx * 32, r0 = by * 32;
  const int tx = threadIdx.x & 31, ty = threadIdx.x >> 5;
#pragma unroll
  for (int i = 0; i < 32; i += 8)
    tile[ty + i][tx] = src[(size_t)(r0 + ty + i) * L + c0 + tx];
  __syncthreads();
#pragma unroll
  for (int i = 0; i < 32; i += 8)
    dst[(size_t)(c0 + ty + i) * R + r0 + tx] = f2bf(tile[tx][ty + i]);
}

// ---------------- fused: u = silu(x@Wd + b) @ Wu, z kept in LDS -------------
// grid (S/128=4, M*B=64) = 256 blocks (1/CU), 512 threads (8 waves).
// Phase 1: z[128 x 256] = silu(x[128 x 1024] @ WdT^T + b). Wave tiling 2x4:
//          wave owns 64 s-rows x 64 d-cols (4x4 frags of 16x16x32).
// z in LDS as 8 k-tiles of [128 rows x 32 k] (staging layout, b128-readable).
// Phase 2: 4 c-tiles of 256: u_tile = z @ WuT^T; A from z LDS, B staged.
// Double-buffered staging throughout (prefetch distance 1).
__global__ __launch_bounds__(512, 2) void fused_adapter(
    const u16* __restrict__ xb, const u16* __restrict__ wdT,
    const u16* __restrict__ wuT, const float* __restrict__ db,
    const int* __restrict__ eidx, float* __restrict__ out) {
  __shared__ __align__(16) u16 smA[2][128 * 32];   // 2 x  8 KB: x staging
  __shared__ __align__(16) u16 smB[2][256 * 32];   // 2 x 16 KB: weight staging
  __shared__ __align__(16) u16 zl[8 * 128 * 32];   // 64 KB: z (8 k-tiles)

  const int pair = blockIdx.y;
  const int m = pair >> 5;
  const int b = pair & 31;
  const int e = eidx[pair];
  const int s0 = blockIdx.x * 128;

  const int tid = threadIdx.x;
  const int lane = tid & 63;
  const int wave = tid >> 6;          // 0..7
  const int quad = lane >> 4;
  const int l16 = lane & 15;

  const int srow = lane >> 2;         // staging row within 16-row group
  const int kc = (lane & 3) * 8;      // staging 16B chunk within 64B row

  const int wr = (wave >> 2) * 64;    // wave s-rows
  const int wc = (wave & 3) * 64;     // wave cols (d in ph1, c in ph2)

  // ---- global bases ----
  const u16* Ab = xb + ((size_t)b * SS + s0) * CC;        // [128 x 1024]
  const u16* Bd = wdT + (size_t)(m * NN + e) * DD * CC;   // [256 x 1024]
  const u16* Bu = wuT + (size_t)(m * NN + e) * CC * DD;   // [1024 x 256]

  // phase-1 staging pointers: wave stages 16 A-rows + 32 B-rows
  const u16* gA = Ab + (size_t)(wave * 16 + srow) * CC + kc;
  const u16* gB0 = Bd + (size_t)(wave * 32 + srow) * CC + kc;
  const u16* gB1 = Bd + (size_t)(wave * 32 + 16 + srow) * CC + kc;
  const int lAo = wave * 16 * 32;
  const int lB0o = (wave * 32) * 32;
  const int lB1o = (wave * 32 + 16) * 32;

  f32x4 acc[4][4];
#pragma unroll
  for (int i = 0; i < 4; ++i)
#pragma unroll
    for (int j = 0; j < 4; ++j) acc[i][j] = (f32x4){0.f, 0.f, 0.f, 0.f};

  // ---- phase 1: K = 1024, double-buffered ----
  async16(gA, &smA[0][lAo]);
  async16(gB0, &smB[0][lB0o]);
  async16(gB1, &smB[0][lB1o]);
  __syncthreads();

  for (int kk = 0; kk < 32; ++kk) {
    const int cur = kk & 1, nxt = cur ^ 1;
    if (kk < 31) {
      const int ko = (kk + 1) * 32;
      async16(gA + ko, &smA[nxt][lAo]);
      async16(gB0 + ko, &smB[nxt][lB0o]);
      async16(gB1 + ko, &smB[nxt][lB1o]);
    } else {
      // prefetch phase-2 g=0 (ct=0, k=0) B-tile into smB[0]
      async16(Bu + (size_t)(wave * 32 + srow) * DD + kc, &smB[nxt][lB0o]);
      async16(Bu + (size_t)(wave * 32 + 16 + srow) * DD + kc, &smB[nxt][lB1o]);
    }
    bf16x8 af[4], bfr[4];
#pragma unroll
    for (int i = 0; i < 4; ++i)
      af[i] = *reinterpret_cast<const bf16x8*>(&smA[cur][(wr + i * 16 + l16) * 32 + quad * 8]);
#pragma unroll
    for (int j = 0; j < 4; ++j)
      bfr[j] = *reinterpret_cast<const bf16x8*>(&smB[cur][(wc + j * 16 + l16) * 32 + quad * 8]);
#pragma unroll
    for (int i = 0; i < 4; ++i)
#pragma unroll
      for (int j = 0; j < 4; ++j)
        acc[i][j] = __builtin_amdgcn_mfma_f32_16x16x32_bf16(af[i], bfr[j], acc[i][j], 0, 0, 0);
    __syncthreads();
  }

  // ---- silu + bias, z -> LDS k-tile layout ----
  const float* bias_p = db + (size_t)(m * NN + e) * DD;
#pragma unroll
  for (int j = 0; j < 4; ++j) {
    const int d = wc + j * 16 + l16;
    const float bias = bias_p[d];
    const int kt = d >> 5;
    const int kl = d & 31;
#pragma unroll
    for (int i = 0; i < 4; ++i) {
      const int zr = wr + i * 16 + quad * 4;
#pragma unroll
      for (int r = 0; r < 4; ++r) {
        float v = acc[i][j][r] + bias;
        v = v / (1.f + __expf(-v));
        zl[(kt * 128 + zr + r) * 32 + kl] = f2bf(v);
      }
    }
  }
  __syncthreads();   // z ready; phase-2 g=0 B-tile drained

  // ---- phase 2: 32 flat iters over (ct, k), double-buffered B ----
  float* ob = out + ((size_t)pair * SS + s0) * CC;

  for (int g = 0; g < 32; ++g) {
    const int cur = g & 1, nxt = cur ^ 1;
    const int ct = g >> 3;
    const int it = g & 7;
    if (g < 31) {
      const int g2 = g + 1;
      const int ct2 = g2 >> 3;
      const int ko2 = (g2 & 7) * 32;
      async16(Bu + (size_t)(ct2 * 256 + wave * 32 + srow) * DD + ko2 + kc, &smB[nxt][lB0o]);
      async16(Bu + (size_t)(ct2 * 256 + wave * 32 + 16 + srow) * DD + ko2 + kc, &smB[nxt][lB1o]);
    }
    if (it == 0) {
#pragma unroll
      for (int i = 0; i < 4; ++i)
#pragma unroll
        for (int j = 0; j < 4; ++j) acc[i][j] = (f32x4){0.f, 0.f, 0.f, 0.f};
    }
    bf16x8 af[4], bfr[4];
#pragma unroll
    for (int i = 0; i < 4; ++i)
      af[i] = *reinterpret_cast<const bf16x8*>(&zl[(it * 128 + wr + i * 16 + l16) * 32 + quad * 8]);
#pragma unroll
    for (int j = 0; j < 4; ++j)
      bfr[j] = *reinterpret_cast<const bf16x8*>(&smB[cur][(wc + j * 16 + l16) * 32 + quad * 8]);
#pragma unroll
    for (int i = 0; i < 4; ++i)
#pragma unroll
      for (int j = 0; j < 4; ++j)
        acc[i][j] = __builtin_amdgcn_mfma_f32_16x16x32_bf16(af[i], bfr[j], acc[i][j], 0, 0, 0);
    if (it == 7) {
#pragma unroll
      for (int j = 0; j < 4; ++j) {
        const int c = ct * 256 + wc + j * 16 + l16;
#pragma unroll
        for (int i = 0; i < 4; ++i) {
          const int sr = wr + i * 16 + quad * 4;
#pragma unroll
          for (int r = 0; r < 4; ++r)
            ob[(size_t)(sr + r) * CC + c] = acc[i][j][r];
        }
      }
    }
    __syncthreads();
  }
}

extern "C" void kernel_launch(void* const* d_in, const int* in_sizes, int n_in,
                              void* d_out, int out_size, void* d_ws, size_t ws_size,
                              hipStream_t stream) {
  const float* x  = (const float*)d_in[0];  // [B,S,C]
  const int* eidx = (const int*)d_in[1];    // [M,B]
  const float* dw = (const float*)d_in[2];  // [M,N,C,D]
  const float* db = (const float*)d_in[3];  // [M,N,D]
  const float* uw = (const float*)d_in[4];  // [M,N,D,C]
  float* out = (float*)d_out;               // [M,B,S,C]

  char* ws = (char*)d_ws;
  u16* xb  = (u16*)(ws);                                   // 32 MB: [B,S,C] bf16
  u16* wdT = (u16*)(ws + (size_t)32 * 1024 * 1024);        //  8 MB: [M,N,D,C] bf16
  u16* wuT = (u16*)(ws + (size_t)40 * 1024 * 1024);        //  8 MB: [M,N,C,D] bf16

  prep<<<dim3(CVT_BLOCKS + 2 * T_BLOCKS), dim3(256), 0, stream>>>(
      x, xb, dw, wdT, uw, wuT);
  fused_adapter<<<dim3(SS / 128, MM * BB), dim3(512), 0, stream>>>(
      xb, wdT, wuT, db, eidx, out);
}

// Round 4
// 271.231 us; speedup vs baseline: 1.0232x; 1.0232x over previous
//
#include <hip/hip_runtime.h>
#include <stdint.h>

typedef unsigned short u16;
typedef __bf16 bf16x8 __attribute__((ext_vector_type(8)));
typedef float f32x4 __attribute__((ext_vector_type(4)));

#define MM 2
#define NN 8
#define CC 1024
#define DD 256
#define BB 32
#define SS 512

__device__ __forceinline__ u16 f2bf(float f) {
  uint32_t u = __float_as_uint(f);
  u += 0x7FFFu + ((u >> 16) & 1u);   // round-to-nearest-even
  return (u16)(u >> 16);
}

__device__ __forceinline__ uint32_t pack2(float a, float b) {
  return (uint32_t)f2bf(a) | ((uint32_t)f2bf(b) << 16);
}

__device__ __forceinline__ void async16(const void* g, void* l) {
  __builtin_amdgcn_global_load_lds(
      (const __attribute__((address_space(1))) uint32_t*)g,
      (__attribute__((address_space(3))) uint32_t*)l, 16, 0, 0);
}

// ---------------- prep: transpose+cvt both weight tensors ----------------
// blocks [0, 4096)     : down_w (C,D) slabs -> (D,C) bf16
// blocks [4096, 8192)  : up_w (D,C) slabs -> (C,D) bf16
#define T_BLOCKS 4096
__global__ __launch_bounds__(256) void prep_w(
    const float* __restrict__ dw, u16* __restrict__ wdT,
    const float* __restrict__ uw, u16* __restrict__ wuT) {
  const int bid = blockIdx.x;
  __shared__ float tile[32][33];
  const float* src;
  u16* dst;
  int R, L, bx, by, slab;
  if (bid < T_BLOCKS) {
    int t = bid;
    slab = t >> 8;
    int t2 = t & 255;
    bx = t2 & 7;  by = t2 >> 3;    // L/32=8, R/32=32
    R = CC; L = DD;
    src = dw; dst = wdT;
  } else {
    int t = bid - T_BLOCKS;
    slab = t >> 8;
    int t2 = t & 255;
    bx = t2 & 31; by = t2 >> 5;    // L/32=32, R/32=8
    R = DD; L = CC;
    src = uw; dst = wuT;
  }
  src += (size_t)slab * R * L;
  dst += (size_t)slab * R * L;
  const int c0 = bx * 32, r0 = by * 32;
  const int tx = threadIdx.x & 31, ty = threadIdx.x >> 5;
#pragma unroll
  for (int i = 0; i < 32; i += 8)
    tile[ty + i][tx] = src[(size_t)(r0 + ty + i) * L + c0 + tx];
  __syncthreads();
#pragma unroll
  for (int i = 0; i < 32; i += 8)
    dst[(size_t)(c0 + ty + i) * R + r0 + tx] = f2bf(tile[tx][ty + i]);
}

// ---------------- fused: u = silu(x@Wd + b) @ Wu, z kept in LDS -------------
// grid (S/128=4, M*B=64) = 256 blocks (1/CU), 512 threads (8 waves).
// x is read directly as fp32 and converted in-register during A staging
// (software-pipelined one K-iter ahead); B staged via global_load_lds dbuf.
__global__ __launch_bounds__(512, 2) void fused_adapter(
    const float* __restrict__ x, const u16* __restrict__ wdT,
    const u16* __restrict__ wuT, const float* __restrict__ db,
    const int* __restrict__ eidx, float* __restrict__ out) {
  __shared__ __align__(16) u16 smA[2][128 * 32];   // 2 x  8 KB: x staging (bf16)
  __shared__ __align__(16) u16 smB[2][256 * 32];   // 2 x 16 KB: weight staging
  __shared__ __align__(16) u16 zl[8 * 128 * 32];   // 64 KB: z (8 k-tiles)

  const int pair = blockIdx.y;
  const int m = pair >> 5;
  const int b = pair & 31;
  const int e = eidx[pair];
  const int s0 = blockIdx.x * 128;

  const int tid = threadIdx.x;
  const int lane = tid & 63;
  const int wave = tid >> 6;          // 0..7
  const int quad = lane >> 4;
  const int l16 = lane & 15;

  const int srow = lane >> 2;         // staging row within 16-row group
  const int kc = (lane & 3) * 8;      // staging 16B chunk within 64B row

  const int wr = (wave >> 2) * 64;    // wave s-rows
  const int wc = (wave & 3) * 64;     // wave cols (d in ph1, c in ph2)

  // ---- global bases ----
  const u16* Bd = wdT + (size_t)(m * NN + e) * DD * CC;   // [256 x 1024]
  const u16* Bu = wuT + (size_t)(m * NN + e) * CC * DD;   // [1024 x 256]

  // A: thread covers row tid>>2, 8-k segment (tid&3)*8
  const int arow = tid >> 2;
  const int akseg = (tid & 3) * 8;
  const float* gAx = x + ((size_t)b * SS + s0 + arow) * CC + akseg;
  const int lAoff = arow * 32 + akseg;

  // B staging: wave stages 32 rows
  const u16* gB0 = Bd + (size_t)(wave * 32 + srow) * CC + kc;
  const u16* gB1 = Bd + (size_t)(wave * 32 + 16 + srow) * CC + kc;
  const int lB0o = (wave * 32) * 32;
  const int lB1o = (wave * 32 + 16) * 32;

  f32x4 acc[4][4];
#pragma unroll
  for (int i = 0; i < 4; ++i)
#pragma unroll
    for (int j = 0; j < 4; ++j) acc[i][j] = (f32x4){0.f, 0.f, 0.f, 0.f};

  // ---- phase 1: K = 1024, double-buffered ----
  {
    float4 a0 = *reinterpret_cast<const float4*>(gAx + 0);
    float4 a1 = *reinterpret_cast<const float4*>(gAx + 4);
    *reinterpret_cast<uint4*>(&smA[0][lAoff]) =
        make_uint4(pack2(a0.x, a0.y), pack2(a0.z, a0.w),
                   pack2(a1.x, a1.y), pack2(a1.z, a1.w));
  }
  async16(gB0, &smB[0][lB0o]);
  async16(gB1, &smB[0][lB1o]);
  __syncthreads();

  for (int kk = 0; kk < 32; ++kk) {
    const int cur = kk & 1, nxt = cur ^ 1;
    float4 n0, n1;
    if (kk < 31) {
      const int ko = (kk + 1) * 32;
      n0 = *reinterpret_cast<const float4*>(gAx + ko + 0);
      n1 = *reinterpret_cast<const float4*>(gAx + ko + 4);
      async16(gB0 + ko, &smB[nxt][lB0o]);
      async16(gB1 + ko, &smB[nxt][lB1o]);
    } else {
      // prefetch phase-2 g=0 (ct=0, k=0) B-tile into the other buffer
      async16(Bu + (size_t)(wave * 32 + srow) * DD + kc, &smB[nxt][lB0o]);
      async16(Bu + (size_t)(wave * 32 + 16 + srow) * DD + kc, &smB[nxt][lB1o]);
    }
    bf16x8 af[4], bfr[4];
#pragma unroll
    for (int i = 0; i < 4; ++i)
      af[i] = *reinterpret_cast<const bf16x8*>(&smA[cur][(wr + i * 16 + l16) * 32 + quad * 8]);
#pragma unroll
    for (int j = 0; j < 4; ++j)
      bfr[j] = *reinterpret_cast<const bf16x8*>(&smB[cur][(wc + j * 16 + l16) * 32 + quad * 8]);
#pragma unroll
    for (int i = 0; i < 4; ++i)
#pragma unroll
      for (int j = 0; j < 4; ++j)
        acc[i][j] = __builtin_amdgcn_mfma_f32_16x16x32_bf16(af[i], bfr[j], acc[i][j], 0, 0, 0);
    if (kk < 31) {
      *reinterpret_cast<uint4*>(&smA[nxt][lAoff]) =
          make_uint4(pack2(n0.x, n0.y), pack2(n0.z, n0.w),
                     pack2(n1.x, n1.y), pack2(n1.z, n1.w));
    }
    __syncthreads();
  }

  // ---- silu + bias, z -> LDS k-tile layout ----
  const float* bias_p = db + (size_t)(m * NN + e) * DD;
#pragma unroll
  for (int j = 0; j < 4; ++j) {
    const int d = wc + j * 16 + l16;
    const float bias = bias_p[d];
    const int kt = d >> 5;
    const int kl = d & 31;
#pragma unroll
    for (int i = 0; i < 4; ++i) {
      const int zr = wr + i * 16 + quad * 4;
#pragma unroll
      for (int r = 0; r < 4; ++r) {
        float v = acc[i][j][r] + bias;
        v = v / (1.f + __expf(-v));
        zl[(kt * 128 + zr + r) * 32 + kl] = f2bf(v);
      }
    }
  }
  __syncthreads();   // z ready; phase-2 g=0 B-tile drained

  // ---- phase 2: 32 flat iters over (ct, k), double-buffered B ----
  float* ob = out + ((size_t)pair * SS + s0) * CC;

  for (int g = 0; g < 32; ++g) {
    const int cur2 = g & 1, nxt2 = cur2 ^ 1;
    const int ct = g >> 3;
    const int it = g & 7;
    if (g < 31) {
      const int g2 = g + 1;
      const int ct2 = g2 >> 3;
      const int ko2 = (g2 & 7) * 32;
      async16(Bu + (size_t)(ct2 * 256 + wave * 32 + srow) * DD + ko2 + kc, &smB[nxt2][lB0o]);
      async16(Bu + (size_t)(ct2 * 256 + wave * 32 + 16 + srow) * DD + ko2 + kc, &smB[nxt2][lB1o]);
    }
    if (it == 0) {
#pragma unroll
      for (int i = 0; i < 4; ++i)
#pragma unroll
        for (int j = 0; j < 4; ++j) acc[i][j] = (f32x4){0.f, 0.f, 0.f, 0.f};
    }
    bf16x8 af[4], bfr[4];
#pragma unroll
    for (int i = 0; i < 4; ++i)
      af[i] = *reinterpret_cast<const bf16x8*>(&zl[(it * 128 + wr + i * 16 + l16) * 32 + quad * 8]);
#pragma unroll
    for (int j = 0; j < 4; ++j)
      bfr[j] = *reinterpret_cast<const bf16x8*>(&smB[cur2][(wc + j * 16 + l16) * 32 + quad * 8]);
#pragma unroll
    for (int i = 0; i < 4; ++i)
#pragma unroll
      for (int j = 0; j < 4; ++j)
        acc[i][j] = __builtin_amdgcn_mfma_f32_16x16x32_bf16(af[i], bfr[j], acc[i][j], 0, 0, 0);
    if (it == 7) {
#pragma unroll
      for (int j = 0; j < 4; ++j) {
        const int c = ct * 256 + wc + j * 16 + l16;
#pragma unroll
        for (int i = 0; i < 4; ++i) {
          const int sr = wr + i * 16 + quad * 4;
#pragma unroll
          for (int r = 0; r < 4; ++r)
            ob[(size_t)(sr + r) * CC + c] = acc[i][j][r];
        }
      }
    }
    __syncthreads();
  }
}

extern "C" void kernel_launch(void* const* d_in, const int* in_sizes, int n_in,
                              void* d_out, int out_size, void* d_ws, size_t ws_size,
                              hipStream_t stream) {
  const float* x  = (const float*)d_in[0];  // [B,S,C]
  const int* eidx = (const int*)d_in[1];    // [M,B]
  const float* dw = (const float*)d_in[2];  // [M,N,C,D]
  const float* db = (const float*)d_in[3];  // [M,N,D]
  const float* uw = (const float*)d_in[4];  // [M,N,D,C]
  float* out = (float*)d_out;               // [M,B,S,C]

  char* ws = (char*)d_ws;
  u16* wdT = (u16*)(ws);                                   //  8 MB: [M,N,D,C] bf16
  u16* wuT = (u16*)(ws + (size_t)8 * 1024 * 1024);         //  8 MB: [M,N,C,D] bf16

  prep_w<<<dim3(2 * T_BLOCKS), dim3(256), 0, stream>>>(dw, wdT, uw, wuT);
  fused_adapter<<<dim3(SS / 128, MM * BB), dim3(512), 0, stream>>>(
      x, wdT, wuT, db, eidx, out);
}